// Round 11
// baseline (334.424 us; speedup 1.0000x reference)
//
#include <hip/hip_runtime.h>
#include <hip/hip_fp16.h>
#include <math.h>

#define N_NODES 100000
#define N_EDGES 1600000
#define IN_DIM 128
#define HEADS 8
#define D1 16
#define D2 8
#define NEG_SLOPE 0.2f

#define NBKT ((N_NODES + 255) / 256)      // 391 buckets of 256 dst nodes
#define PART_CHUNK 4096                   // R16 lesson: bigger chunks -> occupancy collapse
#define BCAP 6144                         // R19: fixed bucket capacity = mean 4096 + 32 sigma
#define BCSTRIDE 32                       // R21: one 128B line per bucket cursor
#define GEMM1_BLOCKS ((N_NODES + 63) / 64)

typedef _Float16 f16x8 __attribute__((ext_vector_type(8)));
typedef float    f32x4 __attribute__((ext_vector_type(4)));

// 16-byte pack of 8 halves.
struct __align__(16) half8 { __half2 a, b, c, d; };

__device__ __forceinline__ f16x8 load_cvt8(const float* p) {
    float4 v0 = *(const float4*)p, v1 = *(const float4*)(p + 4);
    f16x8 r;
    r[0] = (_Float16)v0.x; r[1] = (_Float16)v0.y;
    r[2] = (_Float16)v0.z; r[3] = (_Float16)v0.w;
    r[4] = (_Float16)v1.x; r[5] = (_Float16)v1.y;
    r[6] = (_Float16)v1.z; r[7] = (_Float16)v1.w;
    return r;
}

// DPP row_shr:N add (VALU only). bound_ctrl=true: OOB reads 0.
// row_shr:N: lane i reads lane i-N — accumulation flows toward HIGHER lanes;
// after shr 8,4,2,1 the 16-lane row sum is in lane 15 (R17 bug: stored from
// lane 0). 8-lane group sums land in lanes 7 and 15.
template<int CTRL>
__device__ __forceinline__ float dpp_add(float x) {
    int y = __builtin_amdgcn_update_dpp(0, __builtin_bit_cast(int, x),
                                        CTRL, 0xF, 0xF, true);
    return x + __builtin_bit_cast(float, y);
}

// ---------------------------------------------------------------------------
// MFMA GEMM body + fused score epilogue (DPP reduce, R18-verified). Shared by
// the merged [localcsr || gemm1] kernel and the standalone layer-2 kernel.
// Fragment pattern (guide m90/m92, HW-verified):
//   A-frag: lane reads A[row0+(lane&15)][ks..ks+8), ks=(lane>>4)*8 per 32-k step
//   B-frag: same from Bt rows (Bt = W^T)
//   C/D  : row=(lane>>4)*4+r, col=j*16+(lane&15)
// Score fusion: col j*16+lr == head*D+d flat for BOTH layers.
// XF32: layer-1 reads x fp32, converts in-register (RN, == old convert_x).
// ---------------------------------------------------------------------------
template<int OUTC, int D, bool XF32>
__device__ __forceinline__ void gemm_body(int gb, const void* __restrict__ Ain,
                                          const __half* __restrict__ Bt,
                                          __half* __restrict__ C,
                                          const float* __restrict__ a_s,
                                          const float* __restrict__ a_d,
                                          float* __restrict__ s_src,
                                          float* __restrict__ s_dst,
                                          int n_rows) {
    constexpr int K = 128;
    constexpr int NT = OUTC / 16;      // col tiles: 8 (L1) or 4 (L2)
    int wid  = threadIdx.x >> 6;
    int lane = threadIdx.x & 63;
    int row0 = gb * 64 + wid * 16;
    int lr   = lane & 15;              // M-row within tile (A) / N-col (B)
    int ks   = (lane >> 4) * 8;        // k-slice base within 32-k subtile

    int arow = row0 + lr;
    arow = arow < n_rows ? arow : n_rows - 1;   // clamp tail, stores guarded

    f16x8 a0, a1, a2, a3;
    if constexpr (XF32) {
        const float* ap = (const float*)Ain + (long)arow * K + ks;
        a0 = load_cvt8(ap);
        a1 = load_cvt8(ap + 32);
        a2 = load_cvt8(ap + 64);
        a3 = load_cvt8(ap + 96);
    } else {
        const __half* ap = (const __half*)Ain + (long)arow * K + ks;
        a0 = *(const f16x8*)(ap);
        a1 = *(const f16x8*)(ap + 32);
        a2 = *(const f16x8*)(ap + 64);
        a3 = *(const f16x8*)(ap + 96);
    }

    f32x4 acc[NT];
#pragma unroll
    for (int j = 0; j < NT; ++j) acc[j] = (f32x4)(0.f);

#pragma unroll
    for (int j = 0; j < NT; ++j) {
        const __half* bp = Bt + (long)(j * 16 + lr) * K + ks;
        f16x8 b0 = *(const f16x8*)(bp);
        f16x8 b1 = *(const f16x8*)(bp + 32);
        f16x8 b2 = *(const f16x8*)(bp + 64);
        f16x8 b3 = *(const f16x8*)(bp + 96);
        acc[j] = __builtin_amdgcn_mfma_f32_16x16x32_f16(a0, b0, acc[j], 0, 0, 0);
        acc[j] = __builtin_amdgcn_mfma_f32_16x16x32_f16(a1, b1, acc[j], 0, 0, 0);
        acc[j] = __builtin_amdgcn_mfma_f32_16x16x32_f16(a2, b2, acc[j], 0, 0, 0);
        acc[j] = __builtin_amdgcn_mfma_f32_16x16x32_f16(a3, b3, acc[j], 0, 0, 0);
    }

    // per-lane attention-vector slice (flat index j*16+lr works for both D)
    float asv[NT], adv[NT];
#pragma unroll
    for (int j = 0; j < NT; ++j) {
        asv[j] = a_s[j * 16 + lr];
        adv[j] = a_d[j * 16 + lr];
    }

    int rbase = row0 + (lane >> 4) * 4;
#pragma unroll
    for (int r = 0; r < 4; ++r) {
        int rr = rbase + r;
        bool valid = rr < n_rows;

        // ---- h store ----
        if (valid) {
            __half* cp = C + (long)rr * OUTC + lr;
#pragma unroll
            for (int j = 0; j < NT; ++j)
                cp[j * 16] = __float2half(acc[j][r]);
        }

        // ---- fused scores: DPP row reduction (sums -> high lanes) ----
        float ps[NT], pd[NT];
#pragma unroll
        for (int j = 0; j < NT; ++j) {
            ps[j] = acc[j][r] * asv[j];
            pd[j] = acc[j][r] * adv[j];
        }
        if constexpr (D == 16) {
#pragma unroll
            for (int j = 0; j < NT; ++j) {
                ps[j] = dpp_add<0x118>(ps[j]); ps[j] = dpp_add<0x114>(ps[j]);
                ps[j] = dpp_add<0x112>(ps[j]); ps[j] = dpp_add<0x111>(ps[j]);
                pd[j] = dpp_add<0x118>(pd[j]); pd[j] = dpp_add<0x114>(pd[j]);
                pd[j] = dpp_add<0x112>(pd[j]); pd[j] = dpp_add<0x111>(pd[j]);
            }
            // lane 15 of each 16-row holds the row sum -> 2x 32B stores
            if (valid && lr == 15) {
                float* sp = s_src + rr * 8;
                float* dp = s_dst + rr * 8;
                *(float4*)(sp)     = make_float4(ps[0], ps[1], ps[2], ps[3]);
                *(float4*)(sp + 4) = make_float4(ps[4], ps[5], ps[6], ps[7]);
                *(float4*)(dp)     = make_float4(pd[0], pd[1], pd[2], pd[3]);
                *(float4*)(dp + 4) = make_float4(pd[4], pd[5], pd[6], pd[7]);
            }
        } else {
#pragma unroll
            for (int j = 0; j < NT; ++j) {
                ps[j] = dpp_add<0x114>(ps[j]); ps[j] = dpp_add<0x112>(ps[j]);
                ps[j] = dpp_add<0x111>(ps[j]);
                pd[j] = dpp_add<0x114>(pd[j]); pd[j] = dpp_add<0x112>(pd[j]);
                pd[j] = dpp_add<0x111>(pd[j]);
            }
            // lane 7: sum of lanes 0-7 (head 2j); lane 15: lanes 8-15 (head 2j+1)
            if (valid && lr == 7) {
#pragma unroll
                for (int j = 0; j < NT; ++j) {
                    s_src[rr * 8 + 2 * j] = ps[j];
                    s_dst[rr * 8 + 2 * j] = pd[j];
                }
            }
            if (valid && lr == 15) {
#pragma unroll
                for (int j = 0; j < NT; ++j) {
                    s_src[rr * 8 + 2 * j + 1] = ps[j];
                    s_dst[rr * 8 + 2 * j + 1] = pd[j];
                }
            }
        }
    }
}

// ---------------------------------------------------------------------------
// Weight transpose/cast + bcursor zeroing (first dispatch).
// R21: bcursor is line-padded (NBKT*BCSTRIDE ints = 50KB); convw's 24.5K
// threads cover the zeroing.
// ---------------------------------------------------------------------------
__global__ __launch_bounds__(256)
void convert_w_kernel(const float* __restrict__ W1, const float* __restrict__ W2,
                      __half* __restrict__ Wt1, __half* __restrict__ Wt2,
                      int* __restrict__ bcursor) {
    int idx = blockIdx.x * 256 + threadIdx.x;
    if (idx < NBKT * BCSTRIDE) bcursor[idx] = 0;
    if (idx < 128 * 128) {
        int k = idx / 128, j = idx % 128;
        Wt1[(long)j * 128 + k] = __float2half(W1[idx]);
    } else {
        int i = idx - 128 * 128;
        if (i < 128 * 64) {
            int k = i / 64, j = i % 64;
            Wt2[(long)j * 128 + k] = __float2half(W2[i]);
        }
    }
}

// ---------------------------------------------------------------------------
// CSR phase 1: fixed-capacity bucket partition (R19/R20).
// R21: bcursor[bkt*BCSTRIDE] — one 128B line per bucket. The reserve loop is
// 391 blocks x 391 global atomics; packed 4B counters put ~6K same-line
// atomics on each of ~25 lines (TCC serializes same-line atomics — the
// suspected hidden tens-of-us). Padding spreads them 1 line/bucket.
// ---------------------------------------------------------------------------
__global__ __launch_bounds__(256)
void partition_kernel(const int* __restrict__ src, const int* __restrict__ dst,
                      int* __restrict__ bcursor, int2* __restrict__ bpairs) {
    constexpr int EPT = PART_CHUNK / 256;   // 16 edges per thread
    __shared__ int hist[NBKT];
    for (int i = threadIdx.x; i < NBKT; i += 256) hist[i] = 0;
    __syncthreads();
    int e0 = blockIdx.x * PART_CHUNK;
    int sv[EPT], dv[EPT];
#pragma unroll
    for (int j = 0; j < EPT; ++j) {
        int e = e0 + j * 256 + threadIdx.x;
        bool ok = e < N_EDGES;
        dv[j] = ok ? dst[e] : -1;
        sv[j] = ok ? src[e] : 0;
    }
#pragma unroll
    for (int j = 0; j < EPT; ++j)
        if (dv[j] >= 0) atomicAdd(&hist[dv[j] >> 8], 1);
    __syncthreads();
    // reserve a contiguous range per (block, bucket): one global atomic each
    for (int i = threadIdx.x; i < NBKT; i += 256) {
        int c = hist[i];
        if (c) {
            int r = atomicAdd(&bcursor[i * BCSTRIDE], c);
            hist[i] = i * BCAP + (r < BCAP ? r : BCAP);
        }
    }
    __syncthreads();
#pragma unroll
    for (int j = 0; j < EPT; ++j) {
        if (dv[j] >= 0) {
            int bkt = dv[j] >> 8;
            int pos = atomicAdd(&hist[bkt], 1);
            if (pos < (bkt + 1) * BCAP)       // overflow guard (never fires)
                bpairs[pos] = make_int2(sv[j], dv[j]);
        }
    }
}

// ---------------------------------------------------------------------------
// R20 merged dispatch: blocks [0, NBKT) run CSR phase 2 (localcsr); blocks
// [NBKT, NBKT+GEMM1_BLOCKS) run the layer-1 GEMM (independent work streams).
// ---------------------------------------------------------------------------
__global__ __launch_bounds__(256)
void localcsr_gemm1_kernel(const int* __restrict__ bcursor,
                           const int2* __restrict__ bpairs,
                           int* __restrict__ row_start, int* __restrict__ row_end,
                           int* __restrict__ eidx,
                           const float* __restrict__ x, const __half* __restrict__ Wt1,
                           __half* __restrict__ C,
                           const float* __restrict__ a_s, const float* __restrict__ a_d,
                           float* __restrict__ s_src, float* __restrict__ s_dst) {
    if (blockIdx.x >= NBKT) {
        gemm_body<128, D1, true>(blockIdx.x - NBKT, x, Wt1, C,
                                 a_s, a_d, s_src, s_dst, N_NODES);
        return;
    }
    // ---- localcsr body (R19-verified) ----
    __shared__ int cnt[256];
    __shared__ int sh[256];
    __shared__ int cur[256];
    int b = blockIdx.x;
    int tid = threadIdx.x;
    int n0 = b << 8;
    int m0 = b * BCAP;
    int count = bcursor[b * BCSTRIDE];
    int m1 = m0 + (count < BCAP ? count : BCAP);
    cnt[tid] = 0;
    __syncthreads();
    for (int k = m0 + tid; k < m1; k += 256)
        atomicAdd(&cnt[bpairs[k].y & 255], 1);
    __syncthreads();
    int c = cnt[tid];
    sh[tid] = c;
    __syncthreads();
    int run = c;
    for (int off = 1; off < 256; off <<= 1) {
        int add = (tid >= off) ? sh[tid - off] : 0;
        __syncthreads();
        run += add;
        sh[tid] = run;
        __syncthreads();
    }
    int excl = run - c;
    cur[tid] = m0 + excl;
    if (n0 + tid < N_NODES) {
        row_start[n0 + tid] = m0 + excl;
        row_end[n0 + tid]   = m0 + excl + c;
    }
    __syncthreads();
    for (int k = m0 + tid; k < m1; k += 256) {
        int2 p = bpairs[k];
        int pos = atomicAdd(&cur[p.y & 255], 1);
        eidx[pos] = p.x;
    }
}

// ---------------------------------------------------------------------------
// Standalone layer-2 GEMM (reads fp16 h1out; scores fused via DPP).
// ---------------------------------------------------------------------------
__global__ __launch_bounds__(256)
void gemm2_kernel(const __half* __restrict__ A, const __half* __restrict__ Bt,
                  __half* __restrict__ C,
                  const float* __restrict__ a_s, const float* __restrict__ a_d,
                  float* __restrict__ s_src, float* __restrict__ s_dst) {
    gemm_body<64, D2, false>(blockIdx.x, A, Bt, C, a_s, a_d, s_src, s_dst, N_NODES);
}

// ---------------------------------------------------------------------------
// Wave-per-node fused aggregation + softmax + finalize (fp16 gather payload,
// R15 lane-distributed weights). Plateaued at ~80us across 5 structural
// variants — agg2 shows same time at a fraction of the traffic; treated as
// the structural wall for this loop shape. Unchanged.
// ---------------------------------------------------------------------------
template<int D, bool RELU, typename OT>
__global__ __launch_bounds__(256)
void aggregate_wave_kernel(const int* __restrict__ rs, const int* __restrict__ re,
                           const int* __restrict__ eidx,
                           const __half* __restrict__ h,
                           const float* __restrict__ ssrc, const float* __restrict__ sdst,
                           const float* __restrict__ bias, OT* __restrict__ out) {
    constexpr int F = HEADS * D;       // 128 or 64
    constexpr int EPL = F / 64;        // elements per lane: 2 or 1
    int lane = threadIdx.x & 63;
    int node = blockIdx.x * (256 / 64) + (threadIdx.x >> 6);
    node = __builtin_amdgcn_readfirstlane(node);
    if (node >= N_NODES) return;
    int hd = lane >> 3;                // head owning this lane's slice
    int esl = lane & 7;                // edge slot this lane scores

    float sdv = sdst[node * HEADS + hd];
    float sc0 = ssrc[node * HEADS + hd] + sdv;
    float w0 = __expf(sc0 > 0.f ? sc0 : NEG_SLOPE * sc0);
    float wsum = w0;

    float accx, accy = 0.f;
    if constexpr (EPL == 2) {
        float2 v = __half22float2(*(const __half2*)(h + (long)node * F + lane * 2));
        accx = w0 * v.x; accy = w0 * v.y;
    } else {
        accx = w0 * __half2float(h[(long)node * F + lane]);
    }

    int e0 = rs[node], e1 = re[node];
    int e1m1 = e1 - 1;

    for (int e = e0; e < e1; e += 8) {
        int idx = e + esl;
        int ci = idx < e1m1 ? idx : e1m1;          // clamp: address stays valid
        int s_mine = eidx[ci];                     // 8 distinct, contiguous
        float sc = ssrc[s_mine * HEADS + hd] + sdv;
        float w_mine = __expf(sc > 0.f ? sc : NEG_SLOPE * sc);
        w_mine = (idx < e1) ? w_mine : 0.f;        // kill tail slots

        int grp = lane & 56;                       // base lane of my head row
        if constexpr (EPL == 2) {
#pragma unroll
            for (int i = 0; i < 8; ++i) {
                float wi = __shfl(w_mine, grp + i, 64);
                int   si = __shfl(s_mine, grp + i, 64);
                wsum += wi;
                float2 v = __half22float2(*(const __half2*)(h + (long)si * F + lane * 2));
                accx = fmaf(wi, v.x, accx);
                accy = fmaf(wi, v.y, accy);
            }
        } else {
#pragma unroll
            for (int i = 0; i < 8; ++i) {
                float wi = __shfl(w_mine, grp + i, 64);
                int   si = __shfl(s_mine, grp + i, 64);
                wsum += wi;
                accx = fmaf(wi, __half2float(h[(long)si * F + lane]), accx);
            }
        }
    }

    float inv = 1.f / (wsum + 1e-16f);
    if constexpr (EPL == 2) {
        float2 b = *(const float2*)(bias + lane * 2);
        float ox = accx * inv + b.x;
        float oy = accy * inv + b.y;
        if (RELU) { ox = fmaxf(ox, 0.f); oy = fmaxf(oy, 0.f); }
        if constexpr (sizeof(OT) == 2) {
            *(__half2*)((__half*)out + (long)node * F + lane * 2) = __floats2half2_rn(ox, oy);
        } else {
            *(float2*)((float*)out + (long)node * F + lane * 2) = make_float2(ox, oy);
        }
    } else {
        float o = accx * inv + bias[lane];
        if (RELU) o = fmaxf(o, 0.f);
        if constexpr (sizeof(OT) == 2) {
            ((__half*)out)[(long)node * F + lane] = __float2half(o);
        } else {
            ((float*)out)[(long)node * F + lane] = o;
        }
    }
}

extern "C" void kernel_launch(void* const* d_in, const int* in_sizes, int n_in,
                              void* d_out, int out_size, void* d_ws, size_t ws_size,
                              hipStream_t stream) {
    const float* x   = (const float*)d_in[0];
    const int*   ei  = (const int*)d_in[1];      // [2, N_EDGES] row-major
    const float* W1  = (const float*)d_in[2];
    const float* a1s = (const float*)d_in[3];
    const float* a1d = (const float*)d_in[4];
    const float* b1  = (const float*)d_in[5];
    const float* W2  = (const float*)d_in[6];
    const float* a2s = (const float*)d_in[7];
    const float* a2d = (const float*)d_in[8];
    const float* b2  = (const float*)d_in[9];
    float* out = (float*)d_out;

    const int* src = ei;
    const int* dst = ei + N_EDGES;

    // ---- workspace layout (R19) ----
    float* ws = (float*)d_ws;
    float* bufA = ws;                                  // 51.2MB slot:
                                                       //   [0..25.6MB) h1/h2 fp16
                                                       //   [32MB..41.6MB) padded eidx
    float* bufB = bufA + (size_t)N_NODES * 128;        // 51.2MB slot, time-shared:
                                                       //   padded bpairs (19.2MB) -> h1out
    float* ssrc = bufB + (size_t)N_NODES * 128;        // N*8
    float* sdst = ssrc + (size_t)N_NODES * HEADS;      // N*8
    int* counts    = (int*)(sdst + (size_t)N_NODES * HEADS);  // N ints (carved below)
    int* row_start = counts + N_NODES;                 // N+1
    int* row_end   = row_start + N_NODES + 1;          // N

    int* bcursor = counts + 1024;            // NBKT*BCSTRIDE ints = 50KB (line-padded)
    __half* Wt1  = (__half*)(counts + 1024 + NBKT * BCSTRIDE);          // 8192 ints
    __half* Wt2  = (__half*)(counts + 1024 + NBKT * BCSTRIDE + 8192);   // 4096 ints
    int2* bpairs  = (int2*)bufB;             // NBKT*BCAP*8B = 19.2MB; dead before h1out
    __half* h1out = (__half*)bufB;           // N*128 fp16; written by agg L1
    int* eidx = (int*)((char*)bufA + (size_t)32 * 1024 * 1024);  // NBKT*BCAP ints = 9.6MB

    __half* hbuf = (__half*)bufA;

    // ---- 6 dispatches ----
    convert_w_kernel<<<(128 * 128 + 128 * 64 + 255) / 256, 256, 0, stream>>>(
        W1, W2, Wt1, Wt2, bcursor);
    partition_kernel<<<(N_EDGES + PART_CHUNK - 1) / PART_CHUNK, 256, 0, stream>>>(
        src, dst, bcursor, bpairs);
    // merged: CSR phase 2 (391 blocks) || layer-1 GEMM (1563 blocks)
    localcsr_gemm1_kernel<<<NBKT + GEMM1_BLOCKS, 256, 0, stream>>>(
        bcursor, bpairs, row_start, row_end, eidx,
        x, Wt1, hbuf, a1s, a1d, ssrc, sdst);
    aggregate_wave_kernel<D1, true, __half><<<(N_NODES + 3) / 4, 256, 0, stream>>>(
        row_start, row_end, eidx, hbuf, ssrc, sdst, b1, h1out);
    gemm2_kernel<<<GEMM1_BLOCKS, 256, 0, stream>>>(
        h1out, Wt2, hbuf, a2s, a2d, ssrc, sdst);
    aggregate_wave_kernel<D2, false, float><<<(N_NODES + 3) / 4, 256, 0, stream>>>(
        row_start, row_end, eidx, hbuf, ssrc, sdst, b2, out);
}

// Round 12
// 325.518 us; speedup vs baseline: 1.0274x; 1.0274x over previous
//
#include <hip/hip_runtime.h>
#include <hip/hip_fp16.h>
#include <math.h>

#define N_NODES 100000
#define N_EDGES 1600000
#define IN_DIM 128
#define HEADS 8
#define D1 16
#define D2 8
#define NEG_SLOPE 0.2f

#define NBKT ((N_NODES + 255) / 256)      // 391 buckets of 256 dst nodes
#define PART_CHUNK 4096                   // R16 lesson: bigger chunks -> occupancy collapse
#define BCAP 6144                         // R19: fixed bucket capacity = mean 4096 + 32 sigma
#define BCSTRIDE 32                       // R21: one 128B line per bucket cursor (kept; free)
#define GEMM1_BLOCKS ((N_NODES + 63) / 64)

typedef _Float16 f16x8 __attribute__((ext_vector_type(8)));
typedef float    f32x4 __attribute__((ext_vector_type(4)));

// 16-byte pack of 8 halves.
struct __align__(16) half8 { __half2 a, b, c, d; };

__device__ __forceinline__ f16x8 load_cvt8(const float* p) {
    float4 v0 = *(const float4*)p, v1 = *(const float4*)(p + 4);
    f16x8 r;
    r[0] = (_Float16)v0.x; r[1] = (_Float16)v0.y;
    r[2] = (_Float16)v0.z; r[3] = (_Float16)v0.w;
    r[4] = (_Float16)v1.x; r[5] = (_Float16)v1.y;
    r[6] = (_Float16)v1.z; r[7] = (_Float16)v1.w;
    return r;
}

// DPP row_shr:N add (VALU only). bound_ctrl=true: OOB reads 0.
// row_shr:N: lane i reads lane i-N — accumulation flows toward HIGHER lanes;
// after shr 8,4,2,1 the 16-lane row sum is in lane 15 (R17 bug: stored from
// lane 0). 8-lane group sums land in lanes 7 and 15.
template<int CTRL>
__device__ __forceinline__ float dpp_add(float x) {
    int y = __builtin_amdgcn_update_dpp(0, __builtin_bit_cast(int, x),
                                        CTRL, 0xF, 0xF, true);
    return x + __builtin_bit_cast(float, y);
}

// ---------------------------------------------------------------------------
// MFMA GEMM body + fused score epilogue (DPP reduce, R18-verified).
// R22 change: h-store via LDS restage. Old epilogue issued 32 (OUTC=128) /
// 16 (OUTC=64) scattered 2B global stores PER LANE (stride 32B) — ~50K VMEM
// issue slots per CU in gemm1, the suspected hidden middle cost (invisible
// to byte counters; R21 disproved the atomic-contention theory). New: write
// acc fp16 to a per-wave LDS tile (LDS pipe idle here), read back 16B
// chunks, store global_store_dwordx4 with consecutive lanes on consecutive
// chunks — the wave's 16xOUTC tile is CONTIGUOUS in C, so stores coalesce
// to 1KB/instruction. Global-store instructions/lane: 32 -> 4 (L1), 16 -> 2
// (L2). No barrier: each wave reads only its own LDS region.
// Fragment pattern (guide m90/m92, HW-verified):
//   A-frag: lane reads A[row0+(lane&15)][ks..ks+8), ks=(lane>>4)*8 per 32-k step
//   B-frag: same from Bt rows (Bt = W^T)
//   C/D  : row=(lane>>4)*4+r, col=j*16+(lane&15)
// Score fusion: col j*16+lr == head*D+d flat for BOTH layers.
// XF32: layer-1 reads x fp32, converts in-register (RN, == old convert_x).
// ---------------------------------------------------------------------------
template<int OUTC, int D, bool XF32>
__device__ __forceinline__ void gemm_body(int gb, const void* __restrict__ Ain,
                                          const __half* __restrict__ Bt,
                                          __half* __restrict__ C,
                                          const float* __restrict__ a_s,
                                          const float* __restrict__ a_d,
                                          float* __restrict__ s_src,
                                          float* __restrict__ s_dst,
                                          int n_rows) {
    constexpr int K = 128;
    constexpr int NT = OUTC / 16;      // col tiles: 8 (L1) or 4 (L2)
    int wid  = threadIdx.x >> 6;
    int lane = threadIdx.x & 63;
    int row0 = gb * 64 + wid * 16;
    int lr   = lane & 15;              // M-row within tile (A) / N-col (B)
    int ks   = (lane >> 4) * 8;        // k-slice base within 32-k subtile

    int arow = row0 + lr;
    arow = arow < n_rows ? arow : n_rows - 1;   // clamp tail, stores guarded

    f16x8 a0, a1, a2, a3;
    if constexpr (XF32) {
        const float* ap = (const float*)Ain + (long)arow * K + ks;
        a0 = load_cvt8(ap);
        a1 = load_cvt8(ap + 32);
        a2 = load_cvt8(ap + 64);
        a3 = load_cvt8(ap + 96);
    } else {
        const __half* ap = (const __half*)Ain + (long)arow * K + ks;
        a0 = *(const f16x8*)(ap);
        a1 = *(const f16x8*)(ap + 32);
        a2 = *(const f16x8*)(ap + 64);
        a3 = *(const f16x8*)(ap + 96);
    }

    f32x4 acc[NT];
#pragma unroll
    for (int j = 0; j < NT; ++j) acc[j] = (f32x4)(0.f);

#pragma unroll
    for (int j = 0; j < NT; ++j) {
        const __half* bp = Bt + (long)(j * 16 + lr) * K + ks;
        f16x8 b0 = *(const f16x8*)(bp);
        f16x8 b1 = *(const f16x8*)(bp + 32);
        f16x8 b2 = *(const f16x8*)(bp + 64);
        f16x8 b3 = *(const f16x8*)(bp + 96);
        acc[j] = __builtin_amdgcn_mfma_f32_16x16x32_f16(a0, b0, acc[j], 0, 0, 0);
        acc[j] = __builtin_amdgcn_mfma_f32_16x16x32_f16(a1, b1, acc[j], 0, 0, 0);
        acc[j] = __builtin_amdgcn_mfma_f32_16x16x32_f16(a2, b2, acc[j], 0, 0, 0);
        acc[j] = __builtin_amdgcn_mfma_f32_16x16x32_f16(a3, b3, acc[j], 0, 0, 0);
    }

    // per-lane attention-vector slice (flat index j*16+lr works for both D)
    float asv[NT], adv[NT];
#pragma unroll
    for (int j = 0; j < NT; ++j) {
        asv[j] = a_s[j * 16 + lr];
        adv[j] = a_d[j * 16 + lr];
    }

    // per-wave LDS staging tile (16 rows x OUTC halves; 4 waves/block)
    __shared__ __half stg[4][16 * OUTC];
    __half* sp_ = stg[wid];

    int rbase4 = (lane >> 4) * 4;      // local row base within the wave tile
#pragma unroll
    for (int r = 0; r < 4; ++r) {
        int lrow = rbase4 + r;

        // ---- h staged to LDS (replaces 8/4 scattered 2B global stores) ----
#pragma unroll
        for (int j = 0; j < NT; ++j)
            sp_[lrow * OUTC + j * 16 + lr] = __float2half(acc[j][r]);

        int rr = row0 + lrow;
        bool valid = rr < n_rows;

        // ---- fused scores: DPP row reduction (sums -> high lanes) ----
        float ps[NT], pd[NT];
#pragma unroll
        for (int j = 0; j < NT; ++j) {
            ps[j] = acc[j][r] * asv[j];
            pd[j] = acc[j][r] * adv[j];
        }
        if constexpr (D == 16) {
#pragma unroll
            for (int j = 0; j < NT; ++j) {
                ps[j] = dpp_add<0x118>(ps[j]); ps[j] = dpp_add<0x114>(ps[j]);
                ps[j] = dpp_add<0x112>(ps[j]); ps[j] = dpp_add<0x111>(ps[j]);
                pd[j] = dpp_add<0x118>(pd[j]); pd[j] = dpp_add<0x114>(pd[j]);
                pd[j] = dpp_add<0x112>(pd[j]); pd[j] = dpp_add<0x111>(pd[j]);
            }
            // lane 15 of each 16-row holds the row sum -> 2x 32B stores
            if (valid && lr == 15) {
                float* sp = s_src + rr * 8;
                float* dp = s_dst + rr * 8;
                *(float4*)(sp)     = make_float4(ps[0], ps[1], ps[2], ps[3]);
                *(float4*)(sp + 4) = make_float4(ps[4], ps[5], ps[6], ps[7]);
                *(float4*)(dp)     = make_float4(pd[0], pd[1], pd[2], pd[3]);
                *(float4*)(dp + 4) = make_float4(pd[4], pd[5], pd[6], pd[7]);
            }
        } else {
#pragma unroll
            for (int j = 0; j < NT; ++j) {
                ps[j] = dpp_add<0x114>(ps[j]); ps[j] = dpp_add<0x112>(ps[j]);
                ps[j] = dpp_add<0x111>(ps[j]);
                pd[j] = dpp_add<0x114>(pd[j]); pd[j] = dpp_add<0x112>(pd[j]);
                pd[j] = dpp_add<0x111>(pd[j]);
            }
            // lane 7: sum of lanes 0-7 (head 2j); lane 15: lanes 8-15 (head 2j+1)
            if (valid && lr == 7) {
#pragma unroll
                for (int j = 0; j < NT; ++j) {
                    s_src[rr * 8 + 2 * j] = ps[j];
                    s_dst[rr * 8 + 2 * j] = pd[j];
                }
            }
            if (valid && lr == 15) {
#pragma unroll
                for (int j = 0; j < NT; ++j) {
                    s_src[rr * 8 + 2 * j + 1] = ps[j];
                    s_dst[rr * 8 + 2 * j + 1] = pd[j];
                }
            }
        }
    }

    // ---- wide h store: the wave's 16xOUTC tile is contiguous in C ----
    constexpr int CPR = OUTC / 8;      // 16B chunks per row
    constexpr int CPL = 2 * OUTC / 64; // chunks per lane: 4 (L1) / 2 (L2)
#pragma unroll
    for (int t = 0; t < CPL; ++t) {
        int c = t * 64 + lane;         // consecutive lanes -> consecutive chunks
        int row = c / CPR;
        if (row0 + row < n_rows) {
            half8 v = *(half8*)(sp_ + c * 8);
            *(half8*)(C + (long)row0 * OUTC + c * 8) = v;
        }
    }
}

// ---------------------------------------------------------------------------
// Weight transpose/cast + bcursor zeroing (first dispatch).
// ---------------------------------------------------------------------------
__global__ __launch_bounds__(256)
void convert_w_kernel(const float* __restrict__ W1, const float* __restrict__ W2,
                      __half* __restrict__ Wt1, __half* __restrict__ Wt2,
                      int* __restrict__ bcursor) {
    int idx = blockIdx.x * 256 + threadIdx.x;
    if (idx < NBKT * BCSTRIDE) bcursor[idx] = 0;
    if (idx < 128 * 128) {
        int k = idx / 128, j = idx % 128;
        Wt1[(long)j * 128 + k] = __float2half(W1[idx]);
    } else {
        int i = idx - 128 * 128;
        if (i < 128 * 64) {
            int k = i / 64, j = i % 64;
            Wt2[(long)j * 128 + k] = __float2half(W2[i]);
        }
    }
}

// ---------------------------------------------------------------------------
// CSR phase 1: fixed-capacity bucket partition (R19/R20/R21).
// ---------------------------------------------------------------------------
__global__ __launch_bounds__(256)
void partition_kernel(const int* __restrict__ src, const int* __restrict__ dst,
                      int* __restrict__ bcursor, int2* __restrict__ bpairs) {
    constexpr int EPT = PART_CHUNK / 256;   // 16 edges per thread
    __shared__ int hist[NBKT];
    for (int i = threadIdx.x; i < NBKT; i += 256) hist[i] = 0;
    __syncthreads();
    int e0 = blockIdx.x * PART_CHUNK;
    int sv[EPT], dv[EPT];
#pragma unroll
    for (int j = 0; j < EPT; ++j) {
        int e = e0 + j * 256 + threadIdx.x;
        bool ok = e < N_EDGES;
        dv[j] = ok ? dst[e] : -1;
        sv[j] = ok ? src[e] : 0;
    }
#pragma unroll
    for (int j = 0; j < EPT; ++j)
        if (dv[j] >= 0) atomicAdd(&hist[dv[j] >> 8], 1);
    __syncthreads();
    // reserve a contiguous range per (block, bucket): one global atomic each
    for (int i = threadIdx.x; i < NBKT; i += 256) {
        int c = hist[i];
        if (c) {
            int r = atomicAdd(&bcursor[i * BCSTRIDE], c);
            hist[i] = i * BCAP + (r < BCAP ? r : BCAP);
        }
    }
    __syncthreads();
#pragma unroll
    for (int j = 0; j < EPT; ++j) {
        if (dv[j] >= 0) {
            int bkt = dv[j] >> 8;
            int pos = atomicAdd(&hist[bkt], 1);
            if (pos < (bkt + 1) * BCAP)       // overflow guard (never fires)
                bpairs[pos] = make_int2(sv[j], dv[j]);
        }
    }
}

// ---------------------------------------------------------------------------
// R20 merged dispatch: blocks [0, NBKT) run CSR phase 2 (localcsr); blocks
// [NBKT, NBKT+GEMM1_BLOCKS) run the layer-1 GEMM (independent work streams).
// ---------------------------------------------------------------------------
__global__ __launch_bounds__(256)
void localcsr_gemm1_kernel(const int* __restrict__ bcursor,
                           const int2* __restrict__ bpairs,
                           int* __restrict__ row_start, int* __restrict__ row_end,
                           int* __restrict__ eidx,
                           const float* __restrict__ x, const __half* __restrict__ Wt1,
                           __half* __restrict__ C,
                           const float* __restrict__ a_s, const float* __restrict__ a_d,
                           float* __restrict__ s_src, float* __restrict__ s_dst) {
    if (blockIdx.x >= NBKT) {
        gemm_body<128, D1, true>(blockIdx.x - NBKT, x, Wt1, C,
                                 a_s, a_d, s_src, s_dst, N_NODES);
        return;
    }
    // ---- localcsr body (R19-verified) ----
    __shared__ int cnt[256];
    __shared__ int sh[256];
    __shared__ int cur[256];
    int b = blockIdx.x;
    int tid = threadIdx.x;
    int n0 = b << 8;
    int m0 = b * BCAP;
    int count = bcursor[b * BCSTRIDE];
    int m1 = m0 + (count < BCAP ? count : BCAP);
    cnt[tid] = 0;
    __syncthreads();
    for (int k = m0 + tid; k < m1; k += 256)
        atomicAdd(&cnt[bpairs[k].y & 255], 1);
    __syncthreads();
    int c = cnt[tid];
    sh[tid] = c;
    __syncthreads();
    int run = c;
    for (int off = 1; off < 256; off <<= 1) {
        int add = (tid >= off) ? sh[tid - off] : 0;
        __syncthreads();
        run += add;
        sh[tid] = run;
        __syncthreads();
    }
    int excl = run - c;
    cur[tid] = m0 + excl;
    if (n0 + tid < N_NODES) {
        row_start[n0 + tid] = m0 + excl;
        row_end[n0 + tid]   = m0 + excl + c;
    }
    __syncthreads();
    for (int k = m0 + tid; k < m1; k += 256) {
        int2 p = bpairs[k];
        int pos = atomicAdd(&cur[p.y & 255], 1);
        eidx[pos] = p.x;
    }
}

// ---------------------------------------------------------------------------
// Standalone layer-2 GEMM (reads fp16 h1out; scores fused via DPP).
// ---------------------------------------------------------------------------
__global__ __launch_bounds__(256)
void gemm2_kernel(const __half* __restrict__ A, const __half* __restrict__ Bt,
                  __half* __restrict__ C,
                  const float* __restrict__ a_s, const float* __restrict__ a_d,
                  float* __restrict__ s_src, float* __restrict__ s_dst) {
    gemm_body<64, D2, false>(blockIdx.x, A, Bt, C, a_s, a_d, s_src, s_dst, N_NODES);
}

// ---------------------------------------------------------------------------
// Wave-per-node fused aggregation + softmax + finalize (fp16 gather payload,
// R15 lane-distributed weights). Plateaued at ~80us across 5 structural
// variants — agg2 shows same time at a fraction of the traffic; treated as
// the structural wall for this loop shape. Unchanged.
// ---------------------------------------------------------------------------
template<int D, bool RELU, typename OT>
__global__ __launch_bounds__(256)
void aggregate_wave_kernel(const int* __restrict__ rs, const int* __restrict__ re,
                           const int* __restrict__ eidx,
                           const __half* __restrict__ h,
                           const float* __restrict__ ssrc, const float* __restrict__ sdst,
                           const float* __restrict__ bias, OT* __restrict__ out) {
    constexpr int F = HEADS * D;       // 128 or 64
    constexpr int EPL = F / 64;        // elements per lane: 2 or 1
    int lane = threadIdx.x & 63;
    int node = blockIdx.x * (256 / 64) + (threadIdx.x >> 6);
    node = __builtin_amdgcn_readfirstlane(node);
    if (node >= N_NODES) return;
    int hd = lane >> 3;                // head owning this lane's slice
    int esl = lane & 7;                // edge slot this lane scores

    float sdv = sdst[node * HEADS + hd];
    float sc0 = ssrc[node * HEADS + hd] + sdv;
    float w0 = __expf(sc0 > 0.f ? sc0 : NEG_SLOPE * sc0);
    float wsum = w0;

    float accx, accy = 0.f;
    if constexpr (EPL == 2) {
        float2 v = __half22float2(*(const __half2*)(h + (long)node * F + lane * 2));
        accx = w0 * v.x; accy = w0 * v.y;
    } else {
        accx = w0 * __half2float(h[(long)node * F + lane]);
    }

    int e0 = rs[node], e1 = re[node];
    int e1m1 = e1 - 1;

    for (int e = e0; e < e1; e += 8) {
        int idx = e + esl;
        int ci = idx < e1m1 ? idx : e1m1;          // clamp: address stays valid
        int s_mine = eidx[ci];                     // 8 distinct, contiguous
        float sc = ssrc[s_mine * HEADS + hd] + sdv;
        float w_mine = __expf(sc > 0.f ? sc : NEG_SLOPE * sc);
        w_mine = (idx < e1) ? w_mine : 0.f;        // kill tail slots

        int grp = lane & 56;                       // base lane of my head row
        if constexpr (EPL == 2) {
#pragma unroll
            for (int i = 0; i < 8; ++i) {
                float wi = __shfl(w_mine, grp + i, 64);
                int   si = __shfl(s_mine, grp + i, 64);
                wsum += wi;
                float2 v = __half22float2(*(const __half2*)(h + (long)si * F + lane * 2));
                accx = fmaf(wi, v.x, accx);
                accy = fmaf(wi, v.y, accy);
            }
        } else {
#pragma unroll
            for (int i = 0; i < 8; ++i) {
                float wi = __shfl(w_mine, grp + i, 64);
                int   si = __shfl(s_mine, grp + i, 64);
                wsum += wi;
                accx = fmaf(wi, __half2float(h[(long)si * F + lane]), accx);
            }
        }
    }

    float inv = 1.f / (wsum + 1e-16f);
    if constexpr (EPL == 2) {
        float2 b = *(const float2*)(bias + lane * 2);
        float ox = accx * inv + b.x;
        float oy = accy * inv + b.y;
        if (RELU) { ox = fmaxf(ox, 0.f); oy = fmaxf(oy, 0.f); }
        if constexpr (sizeof(OT) == 2) {
            *(__half2*)((__half*)out + (long)node * F + lane * 2) = __floats2half2_rn(ox, oy);
        } else {
            *(float2*)((float*)out + (long)node * F + lane * 2) = make_float2(ox, oy);
        }
    } else {
        float o = accx * inv + bias[lane];
        if (RELU) o = fmaxf(o, 0.f);
        if constexpr (sizeof(OT) == 2) {
            ((__half*)out)[(long)node * F + lane] = __float2half(o);
        } else {
            ((float*)out)[(long)node * F + lane] = o;
        }
    }
}

extern "C" void kernel_launch(void* const* d_in, const int* in_sizes, int n_in,
                              void* d_out, int out_size, void* d_ws, size_t ws_size,
                              hipStream_t stream) {
    const float* x   = (const float*)d_in[0];
    const int*   ei  = (const int*)d_in[1];      // [2, N_EDGES] row-major
    const float* W1  = (const float*)d_in[2];
    const float* a1s = (const float*)d_in[3];
    const float* a1d = (const float*)d_in[4];
    const float* b1  = (const float*)d_in[5];
    const float* W2  = (const float*)d_in[6];
    const float* a2s = (const float*)d_in[7];
    const float* a2d = (const float*)d_in[8];
    const float* b2  = (const float*)d_in[9];
    float* out = (float*)d_out;

    const int* src = ei;
    const int* dst = ei + N_EDGES;

    // ---- workspace layout (R19) ----
    float* ws = (float*)d_ws;
    float* bufA = ws;                                  // 51.2MB slot:
                                                       //   [0..25.6MB) h1/h2 fp16
                                                       //   [32MB..41.6MB) padded eidx
    float* bufB = bufA + (size_t)N_NODES * 128;        // 51.2MB slot, time-shared:
                                                       //   padded bpairs (19.2MB) -> h1out
    float* ssrc = bufB + (size_t)N_NODES * 128;        // N*8
    float* sdst = ssrc + (size_t)N_NODES * HEADS;      // N*8
    int* counts    = (int*)(sdst + (size_t)N_NODES * HEADS);  // N ints (carved below)
    int* row_start = counts + N_NODES;                 // N+1
    int* row_end   = row_start + N_NODES + 1;          // N

    int* bcursor = counts + 1024;            // NBKT*BCSTRIDE ints (line-padded)
    __half* Wt1  = (__half*)(counts + 1024 + NBKT * BCSTRIDE);          // 8192 ints
    __half* Wt2  = (__half*)(counts + 1024 + NBKT * BCSTRIDE + 8192);   // 4096 ints
    int2* bpairs  = (int2*)bufB;             // NBKT*BCAP*8B = 19.2MB; dead before h1out
    __half* h1out = (__half*)bufB;           // N*128 fp16; written by agg L1
    int* eidx = (int*)((char*)bufA + (size_t)32 * 1024 * 1024);  // NBKT*BCAP ints = 9.6MB

    __half* hbuf = (__half*)bufA;

    // ---- 6 dispatches ----
    convert_w_kernel<<<(128 * 128 + 128 * 64 + 255) / 256, 256, 0, stream>>>(
        W1, W2, Wt1, Wt2, bcursor);
    partition_kernel<<<(N_EDGES + PART_CHUNK - 1) / PART_CHUNK, 256, 0, stream>>>(
        src, dst, bcursor, bpairs);
    // merged: CSR phase 2 (391 blocks) || layer-1 GEMM (1563 blocks)
    localcsr_gemm1_kernel<<<NBKT + GEMM1_BLOCKS, 256, 0, stream>>>(
        bcursor, bpairs, row_start, row_end, eidx,
        x, Wt1, hbuf, a1s, a1d, ssrc, sdst);
    aggregate_wave_kernel<D1, true, __half><<<(N_NODES + 3) / 4, 256, 0, stream>>>(
        row_start, row_end, eidx, hbuf, ssrc, sdst, b1, h1out);
    gemm2_kernel<<<GEMM1_BLOCKS, 256, 0, stream>>>(
        h1out, Wt2, hbuf, a2s, a2d, ssrc, sdst);
    aggregate_wave_kernel<D2, false, float><<<(N_NODES + 3) / 4, 256, 0, stream>>>(
        row_start, row_end, eidx, hbuf, ssrc, sdst, b2, out);
}

// Round 13
// 324.164 us; speedup vs baseline: 1.0317x; 1.0042x over previous
//
#include <hip/hip_runtime.h>
#include <hip/hip_fp16.h>
#include <math.h>

#define N_NODES 100000
#define N_EDGES 1600000
#define IN_DIM 128
#define HEADS 8
#define D1 16
#define D2 8
#define NEG_SLOPE 0.2f

#define NBKT ((N_NODES + 255) / 256)      // 391 buckets of 256 dst nodes
#define PART_CHUNK 4096                   // R16 lesson: bigger chunks -> occupancy collapse
#define BCAP 6144                         // R19: fixed bucket capacity = mean 4096 + 32 sigma
#define BCSTRIDE 32                       // R21: one 128B line per bucket cursor (kept; free)
#define GEMM1_BLOCKS ((N_NODES + 63) / 64)

typedef _Float16 f16x8 __attribute__((ext_vector_type(8)));
typedef float    f32x4 __attribute__((ext_vector_type(4)));

// 16-byte pack of 8 halves.
struct __align__(16) half8 { __half2 a, b, c, d; };

__device__ __forceinline__ f16x8 load_cvt8(const float* p) {
    float4 v0 = *(const float4*)p, v1 = *(const float4*)(p + 4);
    f16x8 r;
    r[0] = (_Float16)v0.x; r[1] = (_Float16)v0.y;
    r[2] = (_Float16)v0.z; r[3] = (_Float16)v0.w;
    r[4] = (_Float16)v1.x; r[5] = (_Float16)v1.y;
    r[6] = (_Float16)v1.z; r[7] = (_Float16)v1.w;
    return r;
}

// DPP row_shr:N add (VALU only). bound_ctrl=true: OOB reads 0.
// row_shr:N: lane i reads lane i-N — accumulation flows toward HIGHER lanes;
// after shr 8,4,2,1 the 16-lane row sum is in lane 15 (R17 bug: stored from
// lane 0). 8-lane group sums land in lanes 7 and 15.
template<int CTRL>
__device__ __forceinline__ float dpp_add(float x) {
    int y = __builtin_amdgcn_update_dpp(0, __builtin_bit_cast(int, x),
                                        CTRL, 0xF, 0xF, true);
    return x + __builtin_bit_cast(float, y);
}

// ---------------------------------------------------------------------------
// MFMA GEMM body + fused score epilogue (DPP reduce, R18-verified; R22 LDS
// restage for wide coalesced h-stores).
// Fragment pattern (guide m90/m92, HW-verified):
//   A-frag: lane reads A[row0+(lane&15)][ks..ks+8), ks=(lane>>4)*8 per 32-k step
//   B-frag: same from Bt rows (Bt = W^T)
//   C/D  : row=(lane>>4)*4+r, col=j*16+(lane&15)
// Score fusion: col j*16+lr == head*D+d flat for BOTH layers.
// XF32: layer-1 reads x fp32, converts in-register (RN, == old convert_x).
// ---------------------------------------------------------------------------
template<int OUTC, int D, bool XF32>
__device__ __forceinline__ void gemm_body(int gb, const void* __restrict__ Ain,
                                          const __half* __restrict__ Bt,
                                          __half* __restrict__ C,
                                          const float* __restrict__ a_s,
                                          const float* __restrict__ a_d,
                                          float* __restrict__ s_src,
                                          float* __restrict__ s_dst,
                                          int n_rows) {
    constexpr int K = 128;
    constexpr int NT = OUTC / 16;      // col tiles: 8 (L1) or 4 (L2)
    int wid  = threadIdx.x >> 6;
    int lane = threadIdx.x & 63;
    int row0 = gb * 64 + wid * 16;
    int lr   = lane & 15;              // M-row within tile (A) / N-col (B)
    int ks   = (lane >> 4) * 8;        // k-slice base within 32-k subtile

    int arow = row0 + lr;
    arow = arow < n_rows ? arow : n_rows - 1;   // clamp tail, stores guarded

    f16x8 a0, a1, a2, a3;
    if constexpr (XF32) {
        const float* ap = (const float*)Ain + (long)arow * K + ks;
        a0 = load_cvt8(ap);
        a1 = load_cvt8(ap + 32);
        a2 = load_cvt8(ap + 64);
        a3 = load_cvt8(ap + 96);
    } else {
        const __half* ap = (const __half*)Ain + (long)arow * K + ks;
        a0 = *(const f16x8*)(ap);
        a1 = *(const f16x8*)(ap + 32);
        a2 = *(const f16x8*)(ap + 64);
        a3 = *(const f16x8*)(ap + 96);
    }

    f32x4 acc[NT];
#pragma unroll
    for (int j = 0; j < NT; ++j) acc[j] = (f32x4)(0.f);

#pragma unroll
    for (int j = 0; j < NT; ++j) {
        const __half* bp = Bt + (long)(j * 16 + lr) * K + ks;
        f16x8 b0 = *(const f16x8*)(bp);
        f16x8 b1 = *(const f16x8*)(bp + 32);
        f16x8 b2 = *(const f16x8*)(bp + 64);
        f16x8 b3 = *(const f16x8*)(bp + 96);
        acc[j] = __builtin_amdgcn_mfma_f32_16x16x32_f16(a0, b0, acc[j], 0, 0, 0);
        acc[j] = __builtin_amdgcn_mfma_f32_16x16x32_f16(a1, b1, acc[j], 0, 0, 0);
        acc[j] = __builtin_amdgcn_mfma_f32_16x16x32_f16(a2, b2, acc[j], 0, 0, 0);
        acc[j] = __builtin_amdgcn_mfma_f32_16x16x32_f16(a3, b3, acc[j], 0, 0, 0);
    }

    // per-lane attention-vector slice (flat index j*16+lr works for both D)
    float asv[NT], adv[NT];
#pragma unroll
    for (int j = 0; j < NT; ++j) {
        asv[j] = a_s[j * 16 + lr];
        adv[j] = a_d[j * 16 + lr];
    }

    // per-wave LDS staging tile (16 rows x OUTC halves; 4 waves/block)
    __shared__ __half stg[4][16 * OUTC];
    __half* sp_ = stg[wid];

    int rbase4 = (lane >> 4) * 4;      // local row base within the wave tile
#pragma unroll
    for (int r = 0; r < 4; ++r) {
        int lrow = rbase4 + r;

        // ---- h staged to LDS (replaces scattered 2B global stores) ----
#pragma unroll
        for (int j = 0; j < NT; ++j)
            sp_[lrow * OUTC + j * 16 + lr] = __float2half(acc[j][r]);

        int rr = row0 + lrow;
        bool valid = rr < n_rows;

        // ---- fused scores: DPP row reduction (sums -> high lanes) ----
        float ps[NT], pd[NT];
#pragma unroll
        for (int j = 0; j < NT; ++j) {
            ps[j] = acc[j][r] * asv[j];
            pd[j] = acc[j][r] * adv[j];
        }
        if constexpr (D == 16) {
#pragma unroll
            for (int j = 0; j < NT; ++j) {
                ps[j] = dpp_add<0x118>(ps[j]); ps[j] = dpp_add<0x114>(ps[j]);
                ps[j] = dpp_add<0x112>(ps[j]); ps[j] = dpp_add<0x111>(ps[j]);
                pd[j] = dpp_add<0x118>(pd[j]); pd[j] = dpp_add<0x114>(pd[j]);
                pd[j] = dpp_add<0x112>(pd[j]); pd[j] = dpp_add<0x111>(pd[j]);
            }
            // lane 15 of each 16-row holds the row sum -> 2x 32B stores
            if (valid && lr == 15) {
                float* sp = s_src + rr * 8;
                float* dp = s_dst + rr * 8;
                *(float4*)(sp)     = make_float4(ps[0], ps[1], ps[2], ps[3]);
                *(float4*)(sp + 4) = make_float4(ps[4], ps[5], ps[6], ps[7]);
                *(float4*)(dp)     = make_float4(pd[0], pd[1], pd[2], pd[3]);
                *(float4*)(dp + 4) = make_float4(pd[4], pd[5], pd[6], pd[7]);
            }
        } else {
#pragma unroll
            for (int j = 0; j < NT; ++j) {
                ps[j] = dpp_add<0x114>(ps[j]); ps[j] = dpp_add<0x112>(ps[j]);
                ps[j] = dpp_add<0x111>(ps[j]);
                pd[j] = dpp_add<0x114>(pd[j]); pd[j] = dpp_add<0x112>(pd[j]);
                pd[j] = dpp_add<0x111>(pd[j]);
            }
            // lane 7: sum of lanes 0-7 (head 2j); lane 15: lanes 8-15 (head 2j+1)
            if (valid && lr == 7) {
#pragma unroll
                for (int j = 0; j < NT; ++j) {
                    s_src[rr * 8 + 2 * j] = ps[j];
                    s_dst[rr * 8 + 2 * j] = pd[j];
                }
            }
            if (valid && lr == 15) {
#pragma unroll
                for (int j = 0; j < NT; ++j) {
                    s_src[rr * 8 + 2 * j + 1] = ps[j];
                    s_dst[rr * 8 + 2 * j + 1] = pd[j];
                }
            }
        }
    }

    // ---- wide h store: the wave's 16xOUTC tile is contiguous in C ----
    constexpr int CPR = OUTC / 8;      // 16B chunks per row
    constexpr int CPL = 2 * OUTC / 64; // chunks per lane: 4 (L1) / 2 (L2)
#pragma unroll
    for (int t = 0; t < CPL; ++t) {
        int c = t * 64 + lane;         // consecutive lanes -> consecutive chunks
        int row = c / CPR;
        if (row0 + row < n_rows) {
            half8 v = *(half8*)(sp_ + c * 8);
            *(half8*)(C + (long)row0 * OUTC + c * 8) = v;
        }
    }
}

// ---------------------------------------------------------------------------
// Weight transpose/cast + bcursor zeroing (first dispatch).
// ---------------------------------------------------------------------------
__global__ __launch_bounds__(256)
void convert_w_kernel(const float* __restrict__ W1, const float* __restrict__ W2,
                      __half* __restrict__ Wt1, __half* __restrict__ Wt2,
                      int* __restrict__ bcursor) {
    int idx = blockIdx.x * 256 + threadIdx.x;
    if (idx < NBKT * BCSTRIDE) bcursor[idx] = 0;
    if (idx < 128 * 128) {
        int k = idx / 128, j = idx % 128;
        Wt1[(long)j * 128 + k] = __float2half(W1[idx]);
    } else {
        int i = idx - 128 * 128;
        if (i < 128 * 64) {
            int k = i / 64, j = i % 64;
            Wt2[(long)j * 128 + k] = __float2half(W2[i]);
        }
    }
}

// ---------------------------------------------------------------------------
// CSR phase 1: fixed-capacity bucket partition (R19/R20/R21).
// ---------------------------------------------------------------------------
__global__ __launch_bounds__(256)
void partition_kernel(const int* __restrict__ src, const int* __restrict__ dst,
                      int* __restrict__ bcursor, int2* __restrict__ bpairs) {
    constexpr int EPT = PART_CHUNK / 256;   // 16 edges per thread
    __shared__ int hist[NBKT];
    for (int i = threadIdx.x; i < NBKT; i += 256) hist[i] = 0;
    __syncthreads();
    int e0 = blockIdx.x * PART_CHUNK;
    int sv[EPT], dv[EPT];
#pragma unroll
    for (int j = 0; j < EPT; ++j) {
        int e = e0 + j * 256 + threadIdx.x;
        bool ok = e < N_EDGES;
        dv[j] = ok ? dst[e] : -1;
        sv[j] = ok ? src[e] : 0;
    }
#pragma unroll
    for (int j = 0; j < EPT; ++j)
        if (dv[j] >= 0) atomicAdd(&hist[dv[j] >> 8], 1);
    __syncthreads();
    // reserve a contiguous range per (block, bucket): one global atomic each
    for (int i = threadIdx.x; i < NBKT; i += 256) {
        int c = hist[i];
        if (c) {
            int r = atomicAdd(&bcursor[i * BCSTRIDE], c);
            hist[i] = i * BCAP + (r < BCAP ? r : BCAP);
        }
    }
    __syncthreads();
#pragma unroll
    for (int j = 0; j < EPT; ++j) {
        if (dv[j] >= 0) {
            int bkt = dv[j] >> 8;
            int pos = atomicAdd(&hist[bkt], 1);
            if (pos < (bkt + 1) * BCAP)       // overflow guard (never fires)
                bpairs[pos] = make_int2(sv[j], dv[j]);
        }
    }
}

// ---------------------------------------------------------------------------
// R20 merged dispatch: blocks [0, NBKT) run CSR phase 2 (localcsr); blocks
// [NBKT, NBKT+GEMM1_BLOCKS) run the layer-1 GEMM (independent work streams).
// ---------------------------------------------------------------------------
__global__ __launch_bounds__(256)
void localcsr_gemm1_kernel(const int* __restrict__ bcursor,
                           const int2* __restrict__ bpairs,
                           int* __restrict__ row_start, int* __restrict__ row_end,
                           int* __restrict__ eidx,
                           const float* __restrict__ x, const __half* __restrict__ Wt1,
                           __half* __restrict__ C,
                           const float* __restrict__ a_s, const float* __restrict__ a_d,
                           float* __restrict__ s_src, float* __restrict__ s_dst) {
    if (blockIdx.x >= NBKT) {
        gemm_body<128, D1, true>(blockIdx.x - NBKT, x, Wt1, C,
                                 a_s, a_d, s_src, s_dst, N_NODES);
        return;
    }
    // ---- localcsr body (R19-verified) ----
    __shared__ int cnt[256];
    __shared__ int sh[256];
    __shared__ int cur[256];
    int b = blockIdx.x;
    int tid = threadIdx.x;
    int n0 = b << 8;
    int m0 = b * BCAP;
    int count = bcursor[b * BCSTRIDE];
    int m1 = m0 + (count < BCAP ? count : BCAP);
    cnt[tid] = 0;
    __syncthreads();
    for (int k = m0 + tid; k < m1; k += 256)
        atomicAdd(&cnt[bpairs[k].y & 255], 1);
    __syncthreads();
    int c = cnt[tid];
    sh[tid] = c;
    __syncthreads();
    int run = c;
    for (int off = 1; off < 256; off <<= 1) {
        int add = (tid >= off) ? sh[tid - off] : 0;
        __syncthreads();
        run += add;
        sh[tid] = run;
        __syncthreads();
    }
    int excl = run - c;
    cur[tid] = m0 + excl;
    if (n0 + tid < N_NODES) {
        row_start[n0 + tid] = m0 + excl;
        row_end[n0 + tid]   = m0 + excl + c;
    }
    __syncthreads();
    for (int k = m0 + tid; k < m1; k += 256) {
        int2 p = bpairs[k];
        int pos = atomicAdd(&cur[p.y & 255], 1);
        eidx[pos] = p.x;
    }
}

// ---------------------------------------------------------------------------
// Standalone layer-2 GEMM (reads fp16 h1out; scores fused via DPP).
// ---------------------------------------------------------------------------
__global__ __launch_bounds__(256)
void gemm2_kernel(const __half* __restrict__ A, const __half* __restrict__ Bt,
                  __half* __restrict__ C,
                  const float* __restrict__ a_s, const float* __restrict__ a_d,
                  float* __restrict__ s_src, float* __restrict__ s_dst) {
    gemm_body<64, D2, false>(blockIdx.x, A, Bt, C, a_s, a_d, s_src, s_dst, N_NODES);
}

// ---------------------------------------------------------------------------
// Wave-per-node fused aggregation + softmax + finalize.
// R23: ISSUE-THROUGHPUT diet. Cycle accounting (agg2: 80us, 192K cyc/CU,
// ~390 waves/CU -> ~500 cyc issue/wave) matched the per-group instruction
// count (~74 instr x 2cyc x 3 groups) — the aggs are instruction-issue
// bound, not bytes (agg2 proved: same 80us at 1/10 the traffic).
// Key fact: s_mine holds the SAME 8 values in every 8-lane head group
// (all groups score the same edges e..e+7), so the si broadcast is
// WAVE-UNIFORM -> v_readlane into SGPR instead of __shfl. Deletes 8 of 16
// shfls/group AND moves the per-lane 64-bit gather address math to the
// SALU (scalar base + lane offset). Identical values -> bitwise-identical
// output.
// ---------------------------------------------------------------------------
template<int D, bool RELU, typename OT>
__global__ __launch_bounds__(256)
void aggregate_wave_kernel(const int* __restrict__ rs, const int* __restrict__ re,
                           const int* __restrict__ eidx,
                           const __half* __restrict__ h,
                           const float* __restrict__ ssrc, const float* __restrict__ sdst,
                           const float* __restrict__ bias, OT* __restrict__ out) {
    constexpr int F = HEADS * D;       // 128 or 64
    constexpr int EPL = F / 64;        // elements per lane: 2 or 1
    int lane = threadIdx.x & 63;
    int node = blockIdx.x * (256 / 64) + (threadIdx.x >> 6);
    node = __builtin_amdgcn_readfirstlane(node);
    if (node >= N_NODES) return;
    int hd = lane >> 3;                // head owning this lane's slice
    int esl = lane & 7;                // edge slot this lane scores

    float sdv = sdst[node * HEADS + hd];
    float sc0 = ssrc[node * HEADS + hd] + sdv;
    float w0 = __expf(sc0 > 0.f ? sc0 : NEG_SLOPE * sc0);
    float wsum = w0;

    float accx, accy = 0.f;
    if constexpr (EPL == 2) {
        float2 v = __half22float2(*(const __half2*)(h + (long)node * F + lane * 2));
        accx = w0 * v.x; accy = w0 * v.y;
    } else {
        accx = w0 * __half2float(h[(long)node * F + lane]);
    }

    int e0 = rs[node], e1 = re[node];
    int e1m1 = e1 - 1;

    for (int e = e0; e < e1; e += 8) {
        int idx = e + esl;
        int ci = idx < e1m1 ? idx : e1m1;          // clamp: address stays valid
        int s_mine = eidx[ci];                     // same 8 values in every group
        float sc = ssrc[s_mine * HEADS + hd] + sdv;
        float w_mine = __expf(sc > 0.f ? sc : NEG_SLOPE * sc);
        w_mine = (idx < e1) ? w_mine : 0.f;        // kill tail slots

        int grp = lane & 56;                       // base lane of my head row
#pragma unroll
        for (int i = 0; i < 8; ++i) {
            // si is wave-uniform (slot i identical across groups): SGPR via
            // readlane; gather becomes scalar-base + lane-offset (coalesced,
            // SALU address math).
            int si = (int)__builtin_amdgcn_readlane((unsigned)s_mine, i);
            float wi = __shfl(w_mine, grp + i, 64);
            wsum += wi;
            if constexpr (EPL == 2) {
                const __half2* hp = (const __half2*)(h + (long)si * F) + lane;
                float2 v = __half22float2(*hp);
                accx = fmaf(wi, v.x, accx);
                accy = fmaf(wi, v.y, accy);
            } else {
                accx = fmaf(wi, __half2float(h[(long)si * F + lane]), accx);
            }
        }
    }

    float inv = 1.f / (wsum + 1e-16f);
    if constexpr (EPL == 2) {
        float2 b = *(const float2*)(bias + lane * 2);
        float ox = accx * inv + b.x;
        float oy = accy * inv + b.y;
        if (RELU) { ox = fmaxf(ox, 0.f); oy = fmaxf(oy, 0.f); }
        if constexpr (sizeof(OT) == 2) {
            *(__half2*)((__half*)out + (long)node * F + lane * 2) = __floats2half2_rn(ox, oy);
        } else {
            *(float2*)((float*)out + (long)node * F + lane * 2) = make_float2(ox, oy);
        }
    } else {
        float o = accx * inv + bias[lane];
        if (RELU) o = fmaxf(o, 0.f);
        if constexpr (sizeof(OT) == 2) {
            ((__half*)out)[(long)node * F + lane] = __float2half(o);
        } else {
            ((float*)out)[(long)node * F + lane] = o;
        }
    }
}

extern "C" void kernel_launch(void* const* d_in, const int* in_sizes, int n_in,
                              void* d_out, int out_size, void* d_ws, size_t ws_size,
                              hipStream_t stream) {
    const float* x   = (const float*)d_in[0];
    const int*   ei  = (const int*)d_in[1];      // [2, N_EDGES] row-major
    const float* W1  = (const float*)d_in[2];
    const float* a1s = (const float*)d_in[3];
    const float* a1d = (const float*)d_in[4];
    const float* b1  = (const float*)d_in[5];
    const float* W2  = (const float*)d_in[6];
    const float* a2s = (const float*)d_in[7];
    const float* a2d = (const float*)d_in[8];
    const float* b2  = (const float*)d_in[9];
    float* out = (float*)d_out;

    const int* src = ei;
    const int* dst = ei + N_EDGES;

    // ---- workspace layout (R19) ----
    float* ws = (float*)d_ws;
    float* bufA = ws;                                  // 51.2MB slot:
                                                       //   [0..25.6MB) h1/h2 fp16
                                                       //   [32MB..41.6MB) padded eidx
    float* bufB = bufA + (size_t)N_NODES * 128;        // 51.2MB slot, time-shared:
                                                       //   padded bpairs (19.2MB) -> h1out
    float* ssrc = bufB + (size_t)N_NODES * 128;        // N*8
    float* sdst = ssrc + (size_t)N_NODES * HEADS;      // N*8
    int* counts    = (int*)(sdst + (size_t)N_NODES * HEADS);  // N ints (carved below)
    int* row_start = counts + N_NODES;                 // N+1
    int* row_end   = row_start + N_NODES + 1;          // N

    int* bcursor = counts + 1024;            // NBKT*BCSTRIDE ints (line-padded)
    __half* Wt1  = (__half*)(counts + 1024 + NBKT * BCSTRIDE);          // 8192 ints
    __half* Wt2  = (__half*)(counts + 1024 + NBKT * BCSTRIDE + 8192);   // 4096 ints
    int2* bpairs  = (int2*)bufB;             // NBKT*BCAP*8B = 19.2MB; dead before h1out
    __half* h1out = (__half*)bufB;           // N*128 fp16; written by agg L1
    int* eidx = (int*)((char*)bufA + (size_t)32 * 1024 * 1024);  // NBKT*BCAP ints = 9.6MB

    __half* hbuf = (__half*)bufA;

    // ---- 6 dispatches ----
    convert_w_kernel<<<(128 * 128 + 128 * 64 + 255) / 256, 256, 0, stream>>>(
        W1, W2, Wt1, Wt2, bcursor);
    partition_kernel<<<(N_EDGES + PART_CHUNK - 1) / PART_CHUNK, 256, 0, stream>>>(
        src, dst, bcursor, bpairs);
    // merged: CSR phase 2 (391 blocks) || layer-1 GEMM (1563 blocks)
    localcsr_gemm1_kernel<<<NBKT + GEMM1_BLOCKS, 256, 0, stream>>>(
        bcursor, bpairs, row_start, row_end, eidx,
        x, Wt1, hbuf, a1s, a1d, ssrc, sdst);
    aggregate_wave_kernel<D1, true, __half><<<(N_NODES + 3) / 4, 256, 0, stream>>>(
        row_start, row_end, eidx, hbuf, ssrc, sdst, b1, h1out);
    gemm2_kernel<<<GEMM1_BLOCKS, 256, 0, stream>>>(
        h1out, Wt2, hbuf, a2s, a2d, ssrc, sdst);
    aggregate_wave_kernel<D2, false, float><<<(N_NODES + 3) / 4, 256, 0, stream>>>(
        row_start, row_end, eidx, hbuf, ssrc, sdst, b2, out);
}